// Round 1
// baseline (23424.960 us; speedup 1.0000x reference)
//
#include <hip/hip_runtime.h>

// Problem constants
#define EDIM 512
#define NL 4
#define NB 32
#define SEQ 48
#define SDD 48
#define DVV 16000
#define NBLK 256
#define NTHR 256
#define NCHUNK 224   // logits chunk blocks (blocks 32..255)

// ws layout (float offsets)
#define WS_WCE 16                              // [32] per-b weighted ce
#define WS_HBUF 64                             // [2][NL][NB][EDIM] h, parity-buffered
#define WS_C (WS_HBUF + 2*NL*NB*EDIM)          // [NL][NB][EDIM] c
#define WS_UPO (WS_C + NL*NB*EDIM)             // [NB][SEQ][EDIM] encoder outputs
#define WS_DE (WS_UPO + NB*SEQ*EDIM)           // [NB][EDIM] decoder LSTM input
#define WS_CEP (WS_DE + NB*EDIM)               // [NB][NCHUNK][4] logits partials (max,sum,lablogit)
#define WS_TOTAL (WS_CEP + NB*NCHUNK*4)
#define ZERO_FLOATS WS_UPO                     // zero bar/wce/hbuf/c each launch

struct Params {
  const int *etok, *elen, *dtok;
  const float *emb1, *emb2;
  const float *Wih1, *Whh1, *bih1, *bhh1;
  const float *W1, *b1, *W2, *b2;
  const float *Wih2, *Whh2, *bih2, *bhh2;
  const float *W3, *b3;
  float *out, *ws;
};

__device__ __forceinline__ float wred_sum(float v) {
#pragma unroll
  for (int i = 32; i > 0; i >>= 1) v += __shfl_xor(v, i, 64);
  return v;
}
__device__ __forceinline__ float wred_max(float v) {
#pragma unroll
  for (int i = 32; i > 0; i >>= 1) v = fmaxf(v, __shfl_xor(v, i, 64));
  return v;
}
__device__ __forceinline__ float sigm(float x) { return 1.f / (1.f + __expf(-x)); }
__device__ __forceinline__ float tanh_f(float x) { return 1.f - 2.f / (__expf(2.f * x) + 1.f); }
__device__ __forceinline__ float dacc(float acc, const float4 a, const float4 b) {
  acc = fmaf(a.x, b.x, acc);
  acc = fmaf(a.y, b.y, acc);
  acc = fmaf(a.z, b.z, acc);
  acc = fmaf(a.w, b.w, acc);
  return acc;
}

// Grid barrier: arrive-count + generation flag in ws (device-scope atomics; memset to 0 each launch).
__device__ __forceinline__ void gsync(int* bar, int ph) {
  __syncthreads();
  if (threadIdx.x == 0) {
    __threadfence();
    int prev = __hip_atomic_fetch_add(&bar[0], 1, __ATOMIC_ACQ_REL, __HIP_MEMORY_SCOPE_AGENT);
    if (prev == NBLK - 1) {
      __hip_atomic_store(&bar[0], 0, __ATOMIC_RELAXED, __HIP_MEMORY_SCOPE_AGENT);
      __hip_atomic_store(&bar[1], ph, __ATOMIC_RELEASE, __HIP_MEMORY_SCOPE_AGENT);
    } else {
      while (__hip_atomic_load(&bar[1], __ATOMIC_ACQUIRE, __HIP_MEMORY_SCOPE_AGENT) < ph)
        __builtin_amdgcn_s_sleep(2);
    }
    __threadfence();
  }
  __syncthreads();
}

// ---- decoder attention + softmax + ctx + W2 (one block per batch row b) ----
__device__ void attn_de(const Params& p, float* ws, float* smem, int tid, int b, int t, int pr) {
  const int wid = tid >> 6, lane = tid & 63;
  const float* h4r = ws + WS_HBUF + (((size_t)pr * NL + (NL - 1)) * NB + b) * EDIM;
  const int k0 = lane << 3;
  const float4 ha = *(const float4*)(h4r + k0);
  const float4 hb = *(const float4*)(h4r + k0 + 4);
  // att_raw[s] = dot(h4, upo[b,s,:]); us[s] = sum(upo[b,s,:])
  for (int s = wid; s < SEQ; s += 4) {
    const float* up = ws + WS_UPO + ((size_t)b * SEQ + s) * EDIM;
    const float4 ua = *(const float4*)(up + k0);
    const float4 ub = *(const float4*)(up + k0 + 4);
    float dv = dacc(dacc(0.f, ua, ha), ub, hb);
    float sv = ua.x + ua.y + ua.z + ua.w + ub.x + ub.y + ub.z + ub.w;
    dv = wred_sum(dv);
    sv = wred_sum(sv);
    if (lane == 0) { smem[s] = dv; smem[64 + s] = sv; }
  }
  __syncthreads();
  // y = att_raw @ W1^T + b1; softmax; ctx = a * upo_sum
  if (wid == 0) {
    float y = -1e30f;
    if (lane < SEQ) {
      y = p.b1[lane];
      for (int s2 = 0; s2 < SEQ; ++s2) y = fmaf(smem[s2], p.W1[lane * SEQ + s2], y);
    }
    const float m = wred_max(y);
    const float ex = (lane < SEQ) ? __expf(y - m) : 0.f;
    const float S = wred_sum(ex);
    if (lane < SEQ) smem[128 + lane] = (ex / S) * smem[64 + lane];
  }
  __syncthreads();
  // de = [ctx | emb2[tok]] @ W2^T + b2
  const int tok = p.dtok[b * SDD + t];
  const float* er = p.emb2 + (size_t)tok * EDIM;
  for (int e = tid; e < EDIM; e += NTHR) {
    const float* w2r = p.W2 + (size_t)e * (SEQ + EDIM);
    float acc = p.b2[e];
    for (int j = 0; j < SEQ; ++j) acc = fmaf(smem[128 + j], w2r[j], acc);
    const float* w2e = w2r + SEQ;
    for (int k = 0; k < EDIM; k += 4)
      acc = dacc(acc, *(const float4*)(er + k), *(const float4*)(w2e + k));
    ws[WS_DE + (size_t)b * EDIM + e] = acc;
  }
}

// ---- logits online-softmax partials for one v-chunk (blocks 32..255 -> ci 0..223) ----
__device__ void logits_partial(const Params& p, float* ws, float* smem, int tid, int ci, int step) {
  const int lo = (DVV * ci) / NCHUNK, hi = (DVV * (ci + 1)) / NCHUNK;
  const int nv = hi - lo;
  const int b = tid & 31, q = tid >> 5;  // q = k-slice 0..7 (64 k each)
  const int pp = step & 1;               // h parity after `step`
  const float* hr = ws + WS_HBUF + (((size_t)pp * NL + (NL - 1)) * NB + b) * EDIM + q * 64;
  float4 hx[16];
#pragma unroll
  for (int i = 0; i < 16; ++i) hx[i] = *(const float4*)(hr + i * 4);
  const int ltok = p.dtok[b * SDD + step + 1];
  const int lab = ltok > 0 ? ltok - 1 : 0;
  float m = -1e30f, ssum = 0.f, lablog = -1e30f;
  const int rounds = (nv + 7) >> 3;
  for (int r = 0; r < rounds; ++r) {
#pragma unroll
    for (int j = 0; j < 8; ++j) {
      const int vi = r * 8 + j;
      float pacc = 0.f;
      if (vi < nv) {
        const float* w = p.W3 + (size_t)(lo + vi) * EDIM + q * 64;
#pragma unroll
        for (int i = 0; i < 16; ++i) pacc = dacc(pacc, hx[i], *(const float4*)(w + i * 4));
      }
      smem[j * 256 + q * 32 + b] = pacc;
    }
    __syncthreads();
    const int vi = r * 8 + q;
    if (vi < nv) {
      const int v = lo + vi;
      float lg = p.b3[v];
#pragma unroll
      for (int q2 = 0; q2 < 8; ++q2) lg += smem[q * 256 + q2 * 32 + b];
      if (lg > m) { ssum = ssum * __expf(m - lg) + 1.f; m = lg; }
      else ssum += __expf(lg - m);
      if (v == lab) lablog = lg;
    }
    __syncthreads();
  }
  // merge 8 q-lanes per b
  smem[2048 + tid] = m;
  smem[2048 + 256 + tid] = ssum;
  smem[2048 + 512 + tid] = lablog;
  __syncthreads();
  if (tid < 32) {
    float M = -1e30f;
#pragma unroll
    for (int q2 = 0; q2 < 8; ++q2) M = fmaxf(M, smem[2048 + q2 * 32 + tid]);
    float S = 0.f, LB = -1e30f;
#pragma unroll
    for (int q2 = 0; q2 < 8; ++q2) {
      const float mm = smem[2048 + q2 * 32 + tid];
      S += smem[2048 + 256 + q2 * 32 + tid] * __expf(mm - M);
      LB = fmaxf(LB, smem[2048 + 512 + q2 * 32 + tid]);
    }
    float* cp = ws + WS_CEP + ((size_t)tid * NCHUNK + ci) * 4;
    cp[0] = M; cp[1] = S; cp[2] = LB;
  }
}

// ---- combine chunk partials -> weighted per-b CE (blocks 0..31, b = blk) ----
__device__ void cefin(const Params& p, float* ws, float* smem, int tid, int b, int step) {
  __syncthreads();  // smem reuse after gate combine
  float m = -1e30f, s = 0.f, lb = -1e30f;
  if (tid < NCHUNK) {
    const float* cp = ws + WS_CEP + ((size_t)b * NCHUNK + tid) * 4;
    m = cp[0]; s = cp[1]; lb = cp[2];
  }
  const int wid = tid >> 6, lane = tid & 63;
  float wm = wred_max(m);
  if (lane == 0) smem[wid] = wm;
  __syncthreads();
  const float M = fmaxf(fmaxf(smem[0], smem[1]), fmaxf(smem[2], smem[3]));
  float sc = s * __expf(m - M);
  sc = wred_sum(sc);
  float wl = wred_max(lb);
  if (lane == 0) { smem[8 + wid] = sc; smem[16 + wid] = wl; }
  __syncthreads();
  if (tid == 0) {
    const float S = smem[8] + smem[9] + smem[10] + smem[11];
    const float LB = fmaxf(fmaxf(smem[16], smem[17]), fmaxf(smem[18], smem[19]));
    const int ltok = p.dtok[b * SDD + step + 1];
    int cnt = 0;
    for (int b2 = 0; b2 < NB; ++b2) cnt += (p.dtok[b2 * SDD + step + 1] != 0);
    const float ce = -(LB - M - __logf(S));
    ws[WS_WCE + b] = (ltok != 0 && cnt > 0) ? ce / (float)cnt : 0.f;
  }
}

// ---- one decoder LSTM layer (all 256 blocks; block = 2 e-columns x 32 b x 4 gates) ----
__device__ void dec_layer(const Params& p, float* ws, float* smem, int tid, int blk, int l, int pr, int pw) {
  const int b = tid & 31, ei = (tid >> 5) & 1, g = tid >> 6;
  const int e = (blk << 1) + ei;
  const float* xrow = (l == 0)
      ? (ws + WS_DE + (size_t)b * EDIM)
      : (ws + WS_HBUF + (((size_t)pw * NL + (l - 1)) * NB + b) * EDIM);
  const float* hrow = ws + WS_HBUF + (((size_t)pr * NL + l) * NB + b) * EDIM;
  const size_t row = (size_t)l * 4 * EDIM + (size_t)g * EDIM + e;
  float acc = p.bih2[row] + p.bhh2[row];
  const float* wi = p.Wih2 + row * EDIM;
  const float* wh = p.Whh2 + row * EDIM;
  for (int k = 0; k < EDIM; k += 4) {
    const float4 x4 = *(const float4*)(xrow + k);
    const float4 h4 = *(const float4*)(hrow + k);
    acc = dacc(acc, x4, *(const float4*)(wi + k));
    acc = dacc(acc, h4, *(const float4*)(wh + k));
  }
  smem[(g << 6) + (ei << 5) + b] = acc;
  __syncthreads();
  if (tid < 64) {
    const int b2 = tid & 31;
    const int e2 = (blk << 1) + (tid >> 5);
    const float ig = sigm(smem[tid]);
    const float fg = sigm(smem[64 + tid]);
    const float gg = tanh_f(smem[128 + tid]);
    const float og = sigm(smem[192 + tid]);
    float* cp = ws + WS_C + ((size_t)l * NB + b2) * EDIM + e2;
    const float cn = fg * (*cp) + ig * gg;
    *cp = cn;
    ws[WS_HBUF + (((size_t)pw * NL + l) * NB + b2) * EDIM + e2] = og * tanh_f(cn);
  }
}

__global__ __launch_bounds__(NTHR) void seq2seq_kernel(Params p) {
  __shared__ float smem[2816];
  const int tid = threadIdx.x;
  const int blk = blockIdx.x;
  float* ws = p.ws;
  int* bar = (int*)ws;
  int ph = 0;
  float total_loss = 0.f;  // block 0 / tid 0 only

  // ================= encoder: wavefront over d = t + l =================
  {
    const int li = blk >> 6;      // layer handled by this block
    const int sb = blk & 63;      // e-range
    const int b = tid & 31;
    const int e = (sb << 3) + (tid >> 5);
    const int len = p.elen[b];
    for (int d = 0; d < SEQ + NL - 1; ++d) {
      const int t = d - li;
      if (t >= 0 && t < SEQ) {
        const bool act = t < len;
        const int tp = t & 1, tq = (t + 1) & 1;  // write / read parity
        const float* xrow = (li == 0)
            ? (p.emb1 + (size_t)p.etok[b * SEQ + t] * EDIM)
            : (ws + WS_HBUF + (((size_t)tp * NL + (li - 1)) * NB + b) * EDIM);
        const float* hrow = ws + WS_HBUF + (((size_t)tq * NL + li) * NB + b) * EDIM;
        float* hw = ws + WS_HBUF + (((size_t)tp * NL + li) * NB + b) * EDIM;
        float hnew = 0.f;
        if (act) {
          const float* wi = p.Wih1 + ((size_t)li * 4 * EDIM + e) * EDIM;
          const float* wh = p.Whh1 + ((size_t)li * 4 * EDIM + e) * EDIM;
          const float* bi = p.bih1 + li * 4 * EDIM;
          const float* bh = p.bhh1 + li * 4 * EDIM;
          float a0 = bi[e] + bh[e];
          float a1 = bi[EDIM + e] + bh[EDIM + e];
          float a2 = bi[2 * EDIM + e] + bh[2 * EDIM + e];
          float a3 = bi[3 * EDIM + e] + bh[3 * EDIM + e];
          for (int k = 0; k < EDIM; k += 4) {
            const float4 x4 = *(const float4*)(xrow + k);
            const float4 h4 = *(const float4*)(hrow + k);
            a0 = dacc(a0, x4, *(const float4*)(wi + k));
            a1 = dacc(a1, x4, *(const float4*)(wi + EDIM * EDIM + k));
            a2 = dacc(a2, x4, *(const float4*)(wi + 2 * EDIM * EDIM + k));
            a3 = dacc(a3, x4, *(const float4*)(wi + 3 * EDIM * EDIM + k));
            a0 = dacc(a0, h4, *(const float4*)(wh + k));
            a1 = dacc(a1, h4, *(const float4*)(wh + EDIM * EDIM + k));
            a2 = dacc(a2, h4, *(const float4*)(wh + 2 * EDIM * EDIM + k));
            a3 = dacc(a3, h4, *(const float4*)(wh + 3 * EDIM * EDIM + k));
          }
          float* cp = ws + WS_C + ((size_t)li * NB + b) * EDIM + e;
          const float ig = sigm(a0), fg = sigm(a1), gg = tanh_f(a2), og = sigm(a3);
          const float cn = fg * (*cp) + ig * gg;
          *cp = cn;
          hnew = og * tanh_f(cn);
          hw[e] = hnew;
        } else {
          hw[e] = hrow[e];  // keep frozen state valid in both parities
        }
        if (li == NL - 1) ws[WS_UPO + ((size_t)b * SEQ + t) * EDIM + e] = act ? hnew : 0.f;
      }
      gsync(bar, ++ph);
    }
  }

  // ================= decoder: 47 steps x 5 phases =================
  for (int t = 0; t < SDD - 1; ++t) {
    const int pr = (t + 1) & 1;  // state parity after step t-1 (t=0 -> encoder final, parity 1)
    const int pw = t & 1;
    // phase A: attention+de (blocks 0..31)  ||  logits partials for step t-1 (blocks 32..255)
    if (blk < NB) attn_de(p, ws, smem, tid, blk, t, pr);
    else if (t > 0) logits_partial(p, ws, smem, tid, blk - NB, t - 1);
    gsync(bar, ++ph);
    for (int l = 0; l < NL; ++l) {
      dec_layer(p, ws, smem, tid, blk, l, pr, pw);
      if (l == 0 && t > 0 && blk < NB) cefin(p, ws, smem, tid, blk, t - 1);
      if (l == 1 && t > 0 && blk == 0 && tid < 64) {
        float v = (tid < NB) ? ws[WS_WCE + tid] : 0.f;
        v = wred_sum(v);
        if (tid == 0) total_loss += v;
      }
      gsync(bar, ++ph);
    }
  }
  // tail: logits + CE for last step (46), then write scalar loss
  if (blk >= NB) logits_partial(p, ws, smem, tid, blk - NB, SDD - 2);
  gsync(bar, ++ph);
  if (blk < NB) cefin(p, ws, smem, tid, blk, SDD - 2);
  gsync(bar, ++ph);
  if (blk == 0 && tid < 64) {
    float v = (tid < NB) ? ws[WS_WCE + tid] : 0.f;
    v = wred_sum(v);
    if (tid == 0) { total_loss += v; p.out[0] = total_loss; }
  }
}

extern "C" void kernel_launch(void* const* d_in, const int* in_sizes, int n_in,
                              void* d_out, int out_size, void* d_ws, size_t ws_size,
                              hipStream_t stream) {
  (void)in_sizes; (void)n_in; (void)out_size; (void)ws_size;
  Params prm;
  prm.etok = (const int*)d_in[0];
  prm.elen = (const int*)d_in[1];
  prm.dtok = (const int*)d_in[2];
  prm.emb1 = (const float*)d_in[3];
  prm.emb2 = (const float*)d_in[4];
  prm.Wih1 = (const float*)d_in[5];
  prm.Whh1 = (const float*)d_in[6];
  prm.bih1 = (const float*)d_in[7];
  prm.bhh1 = (const float*)d_in[8];
  prm.W1  = (const float*)d_in[9];
  prm.b1  = (const float*)d_in[10];
  prm.W2  = (const float*)d_in[11];
  prm.b2  = (const float*)d_in[12];
  prm.Wih2 = (const float*)d_in[13];
  prm.Whh2 = (const float*)d_in[14];
  prm.bih2 = (const float*)d_in[15];
  prm.bhh2 = (const float*)d_in[16];
  prm.W3  = (const float*)d_in[17];
  prm.b3  = (const float*)d_in[18];
  prm.out = (float*)d_out;
  prm.ws  = (float*)d_ws;
  // zero: barrier(2 ints) + wce + hbuf + c  (ws is poisoned 0xAA before every launch)
  hipMemsetAsync(d_ws, 0, (size_t)ZERO_FLOATS * sizeof(float), stream);
  void* args[] = { &prm };
  hipLaunchCooperativeKernel((const void*)seq2seq_kernel, dim3(NBLK), dim3(NTHR), args, 0, stream);
}

// Round 2
// 22188.829 us; speedup vs baseline: 1.0557x; 1.0557x over previous
//
#include <hip/hip_runtime.h>

#define EDIM 512
#define NL 4
#define NB 32
#define SEQ 48
#define SDD 48
#define DVV 16000
#define NBLK 256
#define NTHR 1024
#define NTILES (DVV/16)   // 1000 vocab tiles of 16

// ---- ws layout (byte offsets) ----
#define BAR_OFF 0
#define WCE_OFF 256
#define H3F_OFF 512                                  // [32][512] f32 top-layer h (for attention)
#define HBF_OFF (H3F_OFF + NB*EDIM*4)                // [2][4][32][512] bf16 h (parity-buffered)
#define ZERO_BYTES (HBF_OFF + 2*NL*NB*EDIM*2)        // memset 0 .. here (bar + hbf zeros)
#define DEB_OFF ZERO_BYTES                           // [32][512] bf16 decoder LSTM input
#define CWS_OFF (DEB_OFF + NB*EDIM*2)                // [4][32][512] f32 c handoff enc->dec
#define UPO_OFF (CWS_OFF + (size_t)NL*NB*EDIM*4)     // [32][48][512] bf16 encoder outputs
#define EXB_OFF (UPO_OFF + (size_t)NB*SEQ*EDIM*2)    // [32][48][512] bf16 encoder embeddings
#define CEP_OFF (EXB_OFF + (size_t)NB*SEQ*EDIM*2)    // [32][1000][4] f32 logits partials
#define WI1_OFF (CEP_OFF + (size_t)NB*NTILES*4*4)
#define WH1_OFF (WI1_OFF + (size_t)NL*4*EDIM*EDIM*2)
#define WI2_OFF (WH1_OFF + (size_t)NL*4*EDIM*EDIM*2)
#define WH2_OFF (WI2_OFF + (size_t)NL*4*EDIM*EDIM*2)
#define W3B_OFF (WH2_OFF + (size_t)NL*4*EDIM*EDIM*2)
// total ~54.2 MB of ws

typedef __bf16 bf16x8 __attribute__((ext_vector_type(8)));
typedef float floatx4 __attribute__((ext_vector_type(4)));
typedef unsigned int uint4e __attribute__((ext_vector_type(4)));
typedef unsigned short ushort4e __attribute__((ext_vector_type(4)));

struct Params {
  const int *etok, *elen, *dtok;
  const float *emb2;
  const float *bih1, *bhh1;
  const float *W1, *b1, *W2, *b2;
  const float *bih2, *bhh2;
  const float *b3;
  float* out;
  char* ws;
};

__device__ __forceinline__ float wred_sum(float v) {
#pragma unroll
  for (int i = 32; i > 0; i >>= 1) v += __shfl_xor(v, i, 64);
  return v;
}
__device__ __forceinline__ float wred_max(float v) {
#pragma unroll
  for (int i = 32; i > 0; i >>= 1) v = fmaxf(v, __shfl_xor(v, i, 64));
  return v;
}
__device__ __forceinline__ float sigm(float x) { return 1.f / (1.f + __expf(-x)); }
__device__ __forceinline__ float tanh_f(float x) { return 1.f - 2.f / (__expf(2.f * x) + 1.f); }
__device__ __forceinline__ unsigned short f2bf(float f) {  // RNE fp32->bf16
  unsigned int u = __float_as_uint(f);
  return (unsigned short)((u + 0x7fffu + ((u >> 16) & 1u)) >> 16);
}
__device__ __forceinline__ float bf2f(unsigned short u) {
  return __uint_as_float(((unsigned int)u) << 16);
}
__device__ __forceinline__ bf16x8 ld_bf8(const unsigned short* p) {
  return __builtin_bit_cast(bf16x8, *(const uint4e*)p);
}
__device__ __forceinline__ floatx4 mfma16(bf16x8 a, bf16x8 b, floatx4 c) {
  return __builtin_amdgcn_mfma_f32_16x16x32_bf16(a, b, c, 0, 0, 0);
}

// grid barrier: monotonic arrive count, no reset race
__device__ __forceinline__ void gsync(int* bar, int ph) {
  __syncthreads();
  if (threadIdx.x == 0) {
    __threadfence();
    __hip_atomic_fetch_add(&bar[0], 1, __ATOMIC_ACQ_REL, __HIP_MEMORY_SCOPE_AGENT);
    const int target = ph * NBLK;
    while (__hip_atomic_load(&bar[0], __ATOMIC_ACQUIRE, __HIP_MEMORY_SCOPE_AGENT) < target)
      __builtin_amdgcn_s_sleep(1);
    __threadfence();
  }
  __syncthreads();
}

// One 4-gate LSTM GEMM slice: block computes gates[32 b][4 g][16 e] for e-range et*16..+16.
// waves: wid = ks*4+... actually g = wid&3, ks = wid>>2 (K split 4). Partials -> sm_parts.
// parts layout: idx = ((ks*4+g)*2+mt)*256 + r*64 + lane
__device__ void gemm4g(const unsigned short* Wi, const unsigned short* Wh,
                       const unsigned short* xsrc, int xstr, const unsigned short* hsrc,
                       int et, int tid, float* parts) {
  const int wid = tid >> 6, lane = tid & 63, ln = lane & 15, kq = lane >> 4;
  const int g = wid & 3, ks = wid >> 2;
  const size_t n = (size_t)g * 512 + et * 16 + ln;
  const bool isH = (ks >= 2);
  const unsigned short* wr = (isH ? Wh : Wi) + n * EDIM;
  const unsigned short* ap = isH ? hsrc : xsrc;
  const int as = isH ? EDIM : xstr;
  const unsigned short* a0b = ap + (size_t)ln * as;
  const unsigned short* a1b = ap + (size_t)(16 + ln) * as;
  const int k0 = (ks & 1) * 256 + kq * 8;
  floatx4 acc0 = {0.f, 0.f, 0.f, 0.f}, acc1 = {0.f, 0.f, 0.f, 0.f};
#pragma unroll
  for (int c8 = 0; c8 < 8; ++c8) {
    const int kk = k0 + c8 * 32;
    bf16x8 bf = ld_bf8(wr + kk);
    bf16x8 a0 = ld_bf8(a0b + kk);
    bf16x8 a1 = ld_bf8(a1b + kk);
    acc0 = mfma16(a0, bf, acc0);
    acc1 = mfma16(a1, bf, acc1);
  }
  const int base = ((ks * 4 + g) * 2) * 256 + lane;
#pragma unroll
  for (int r = 0; r < 4; ++r) {
    parts[base + r * 64] = acc0[r];
    parts[base + 256 + r * 64] = acc1[r];
  }
}

// combine K-split partials + bias -> sm_gates[g*512 + b*16 + ln]
__device__ void gate_combine(const float* parts, float* gates,
                             const float* bi, const float* bh, int et, int tid) {
  for (int v = tid; v < 2048; v += NTHR) {
    const int ln = v & 15, b = (v >> 4) & 31, g = v >> 9;
    const int mt = b >> 4, kq = (b >> 2) & 3, r = b & 3;
    const int lane = kq * 16 + ln;
    float s = 0.f;
#pragma unroll
    for (int ks = 0; ks < 4; ++ks)
      s += parts[((ks * 4 + g) * 2 + mt) * 256 + r * 64 + lane];
    const int n = g * 512 + et * 16 + ln;
    gates[v] = s + bi[n] + bh[n];
  }
}

__global__ __launch_bounds__(NTHR) void seq2seq_kernel(Params p) {
  __shared__ float sm_parts[8192];   // 32 KB K-split partials
  __shared__ float sm_gates[2048];   // 8 KB combined gates
  __shared__ float sm_c[2048];       // 8 KB c-state [l][b][ln] (enc: l=0 slot only)
  __shared__ float sm_attn[768];     // A:0..47 raw att, U:64.. upo_sum, C:128.. ctx, E:192.. emb2 row
  const int tid = threadIdx.x, blk = blockIdx.x;
  char* wsb = p.ws;
  int* bar = (int*)wsb;
  float* wce = (float*)(wsb + WCE_OFF);
  float* h3f = (float*)(wsb + H3F_OFF);
  unsigned short* hbf = (unsigned short*)(wsb + HBF_OFF);
  unsigned short* deb = (unsigned short*)(wsb + DEB_OFF);
  float* cws = (float*)(wsb + CWS_OFF);
  unsigned short* upo = (unsigned short*)(wsb + UPO_OFF);
  unsigned short* exb = (unsigned short*)(wsb + EXB_OFF);
  float* cep = (float*)(wsb + CEP_OFF);
  const unsigned short* wi1 = (const unsigned short*)(wsb + WI1_OFF);
  const unsigned short* wh1 = (const unsigned short*)(wsb + WH1_OFF);
  const unsigned short* wi2 = (const unsigned short*)(wsb + WI2_OFF);
  const unsigned short* wh2 = (const unsigned short*)(wsb + WH2_OFF);
  const unsigned short* w3b = (const unsigned short*)(wsb + W3B_OFF);
  int ph = 0;
  float total_loss = 0.f;  // lives in blk0/tid512

  // ================= encoder: wavefront over d = t + li =================
  if (blk < 128) {
    const int li = blk >> 5, et = blk & 31;
    sm_c[tid] = 0.f; sm_c[tid + 1024] = 0.f;
    __syncthreads();
    for (int d = 0; d < SEQ + NL - 1; ++d) {
      const int t = d - li;
      if (t >= 0 && t < SEQ) {
        const int tp = t & 1, tq = tp ^ 1;
        const unsigned short* xsrc; int xstr;
        if (li == 0) { xsrc = exb + (size_t)t * EDIM; xstr = SEQ * EDIM; }
        else { xsrc = hbf + ((size_t)tp * NL + (li - 1)) * NB * EDIM; xstr = EDIM; }
        const unsigned short* hsrc = hbf + ((size_t)tq * NL + li) * NB * EDIM;
        gemm4g(wi1 + (size_t)li * 2048 * EDIM, wh1 + (size_t)li * 2048 * EDIM,
               xsrc, xstr, hsrc, et, tid, sm_parts);
        __syncthreads();
        gate_combine(sm_parts, sm_gates, p.bih1 + li * 4 * EDIM, p.bhh1 + li * 4 * EDIM, et, tid);
        __syncthreads();
        if (tid < 512) {
          const int b = tid >> 4, ln = tid & 15, e = et * 16 + ln;
          const bool act = t < p.elen[b];
          const size_t hup = ((size_t)tp * NL + li) * NB * EDIM + (size_t)b * EDIM + e;
          const size_t hdn = ((size_t)tq * NL + li) * NB * EDIM + (size_t)b * EDIM + e;
          unsigned short hnew;
          if (act) {
            const float ig = sigm(sm_gates[tid]);
            const float fg = sigm(sm_gates[512 + tid]);
            const float gg = tanh_f(sm_gates[1024 + tid]);
            const float og = sigm(sm_gates[1536 + tid]);
            const float cn = fg * sm_c[tid] + ig * gg;
            sm_c[tid] = cn;
            const float h = og * tanh_f(cn);
            hnew = f2bf(h);
            if (li == 3) h3f[b * EDIM + e] = h;
          } else {
            hnew = hbf[hdn];
          }
          hbf[hup] = hnew;
          if (li == 3) upo[((size_t)b * SEQ + t) * EDIM + e] = act ? hnew : (unsigned short)0;
        }
        if (t == SEQ - 1) {  // dump c for decoder handoff (uniform branch)
          __syncthreads();
          if (tid < 512) {
            const int b = tid >> 4, ln = tid & 15;
            cws[((size_t)li * NB + b) * EDIM + et * 16 + ln] = sm_c[tid];
          }
        }
      }
      gsync(bar, ++ph);
    }
  } else {
    for (int d = 0; d < SEQ + NL - 1; ++d) gsync(bar, ++ph);
  }

  // ================= decoder: 47 steps =================
  for (int t = 0; t < SDD - 1; ++t) {
    const int pw = t & 1, pr = pw ^ 1;
    // ---- phase A: attention+de (blocks 0..31) || logits t-1 (blocks 32+) ----
    if (blk < NB) {
      const int b = blk;
      const int wid = tid >> 6, lane = tid & 63;
      const float* h3r = h3f + b * EDIM + lane * 8;
      float hq[8];
      const float4 h4a = *(const float4*)h3r;
      const float4 h4b = *(const float4*)(h3r + 4);
      hq[0]=h4a.x; hq[1]=h4a.y; hq[2]=h4a.z; hq[3]=h4a.w;
      hq[4]=h4b.x; hq[5]=h4b.y; hq[6]=h4b.z; hq[7]=h4b.w;
      const int tok = p.dtok[b * SDD + t];
      if (tid < EDIM) sm_attn[192 + tid] = p.emb2[(size_t)tok * EDIM + tid];
      for (int s = wid; s < SEQ; s += 16) {
        const unsigned short* up = upo + ((size_t)b * SEQ + s) * EDIM + lane * 8;
        const uint4e uv = *(const uint4e*)up;
        float dv = 0.f, sv = 0.f;
#pragma unroll
        for (int j = 0; j < 4; ++j) {
          const unsigned int w = uv[j];
          const float lo = __uint_as_float(w << 16);
          const float hi = __uint_as_float(w & 0xffff0000u);
          dv = fmaf(lo, hq[2 * j], dv); sv += lo;
          dv = fmaf(hi, hq[2 * j + 1], dv); sv += hi;
        }
        dv = wred_sum(dv); sv = wred_sum(sv);
        if (lane == 0) { sm_attn[s] = dv; sm_attn[64 + s] = sv; }
      }
      if (t == 0 && tid >= 512) {  // load c handoff into LDS
#pragma unroll
        for (int j = 0; j < 4; ++j) {
          const int v = (tid - 512) * 4 + j;
          const int l = v >> 9, rem = v & 511, b2 = rem >> 4, ln = rem & 15;
          sm_c[v] = cws[((size_t)l * NB + b2) * EDIM + blk * 16 + ln];
        }
      }
      if (t >= 2 && blk == 0 && wid == 8) {  // accumulate loss of step t-2
        float v = (lane < NB) ? wce[lane] : 0.f;
        v = wred_sum(v);
        if (lane == 0) total_loss += v;
      }
      __syncthreads();
      if (wid == 0) {
        float y = -1e30f;
        if (lane < SEQ) {
          y = p.b1[lane];
          const float* w1r = p.W1 + lane * SEQ;
          for (int s = 0; s < SEQ; ++s) y = fmaf(sm_attn[s], w1r[s], y);
        }
        const float m = wred_max(y);
        const float ex = (lane < SEQ) ? __expf(y - m) : 0.f;
        const float S = wred_sum(ex);
        if (lane < SEQ) sm_attn[128 + lane] = (ex / S) * sm_attn[64 + lane];
      }
      __syncthreads();
      if (tid < EDIM) {
        const int e = tid;
        const float* w2r = p.W2 + (size_t)e * (SEQ + EDIM);
        float acc = p.b2[e];
        for (int j = 0; j < SEQ; ++j) acc = fmaf(sm_attn[128 + j], w2r[j], acc);
        const float* w2e = w2r + SEQ;
        const float* er = sm_attn + 192;
        for (int k = 0; k < EDIM; k += 4) {
          const float4 wv = *(const float4*)(w2e + k);
          acc = fmaf(er[k], wv.x, acc);
          acc = fmaf(er[k + 1], wv.y, acc);
          acc = fmaf(er[k + 2], wv.z, acc);
          acc = fmaf(er[k + 3], wv.w, acc);
        }
        deb[b * EDIM + e] = f2bf(acc);
      }
    } else if (t >= 1) {
      // logits for step t-1 via MFMA; h parity (t-1)&1 == pr
      const int idx = (blk - 32) * 16 + (tid >> 6);
      if (idx < NTILES) {
        const int lane = tid & 63, ln = lane & 15, kq = lane >> 4;
        const unsigned short* wrow = w3b + ((size_t)idx * 16 + ln) * EDIM + kq * 8;
        const unsigned short* arow = hbf + ((size_t)pr * NL + 3) * NB * EDIM;
        const unsigned short* a0p = arow + (size_t)ln * EDIM + kq * 8;
        const unsigned short* a1p = a0p + 16 * EDIM;
        floatx4 acc0 = {0.f,0.f,0.f,0.f}, acc1 = {0.f,0.f,0.f,0.f};
#pragma unroll
        for (int c = 0; c < 16; ++c) {
          bf16x8 bf = ld_bf8(wrow + c * 32);
          bf16x8 a0 = ld_bf8(a0p + c * 32);
          bf16x8 a1 = ld_bf8(a1p + c * 32);
          acc0 = mfma16(a0, bf, acc0);
          acc1 = mfma16(a1, bf, acc1);
        }
        const float bv = p.b3[idx * 16 + ln];
        const int v = idx * 16 + ln;
        const int step = t - 1;
#pragma unroll
        for (int mt = 0; mt < 2; ++mt) {
#pragma unroll
          for (int r = 0; r < 4; ++r) {
            const int b = mt * 16 + kq * 4 + r;
            const int ltok = p.dtok[b * SDD + step + 1];
            const int lab = (ltok > 0) ? ltok - 1 : 0;
            const float lv = (mt ? acc1[r] : acc0[r]) + bv;
            float m = lv, lb = (v == lab) ? lv : -1e30f;
#pragma unroll
            for (int st = 1; st < 16; st <<= 1) m = fmaxf(m, __shfl_xor(m, st, 64));
            float se = __expf(lv - m);
#pragma unroll
            for (int st = 1; st < 16; st <<= 1) se += __shfl_xor(se, st, 64);
#pragma unroll
            for (int st = 1; st < 16; st <<= 1) lb = fmaxf(lb, __shfl_xor(lb, st, 64));
            if (ln == 0) {
              float* cp = cep + ((size_t)b * NTILES + idx) * 4;
              cp[0] = m; cp[1] = se; cp[2] = lb;
            }
          }
        }
      }
    }
    gsync(bar, ++ph);
    // ---- phases G0..G3 ----
    for (int l = 0; l < NL; ++l) {
      if (blk < NB) {
        const unsigned short* xsrc = (l == 0) ? deb : hbf + ((size_t)pw * NL + (l - 1)) * NB * EDIM;
        const unsigned short* hsrc = hbf + ((size_t)pr * NL + l) * NB * EDIM;
        gemm4g(wi2 + (size_t)l * 2048 * EDIM, wh2 + (size_t)l * 2048 * EDIM,
               xsrc, EDIM, hsrc, blk, tid, sm_parts);
        __syncthreads();
        gate_combine(sm_parts, sm_gates, p.bih2 + l * 4 * EDIM, p.bhh2 + l * 4 * EDIM, blk, tid);
        __syncthreads();
        if (tid < 512) {
          const int b = tid >> 4, ln = tid & 15, e = blk * 16 + ln;
          const float ig = sigm(sm_gates[tid]);
          const float fg = sigm(sm_gates[512 + tid]);
          const float gg = tanh_f(sm_gates[1024 + tid]);
          const float og = sigm(sm_gates[1536 + tid]);
          const float cn = fg * sm_c[l * 512 + tid] + ig * gg;
          sm_c[l * 512 + tid] = cn;
          const float h = og * tanh_f(cn);
          hbf[((size_t)pw * NL + l) * NB * EDIM + (size_t)b * EDIM + e] = f2bf(h);
          if (l == 3) h3f[b * EDIM + e] = h;
        }
      } else if (l == 0 && blk >= 32 && blk < 64 && t >= 1) {
        // combine logits partials of step t-1 -> wce[b]
        const int b = blk - 32;
        float m = -1e30f, s = 0.f, lb = -1e30f;
        if (tid < NTILES) {
          const float* cp = cep + ((size_t)b * NTILES + tid) * 4;
          m = cp[0]; s = cp[1]; lb = cp[2];
        }
        const int wid = tid >> 6, lane = tid & 63;
        const float M = wred_max(m);
        float sc = s * __expf(m - M);
        sc = wred_sum(sc);
        const float wl = wred_max(lb);
        if (lane == 0) { sm_parts[wid] = M; sm_parts[16 + wid] = sc; sm_parts[32 + wid] = wl; }
        __syncthreads();
        if (tid == 0) {
          float M2 = -1e30f, LB = -1e30f;
          for (int w = 0; w < 16; ++w) M2 = fmaxf(M2, sm_parts[w]);
          float S = 0.f;
          for (int w = 0; w < 16; ++w) S += sm_parts[16 + w] * __expf(sm_parts[w] - M2);
          for (int w = 0; w < 16; ++w) LB = fmaxf(LB, sm_parts[32 + w]);
          const int step = t - 1;
          const int ltok = p.dtok[b * SDD + step + 1];
          int cnt = 0;
          for (int b2 = 0; b2 < NB; ++b2) cnt += (p.dtok[b2 * SDD + step + 1] != 0);
          const float ce = -(lb * 0.f + (LB - M2 - __logf(S)));  // = LB - logsumexp
          wce[b] = (ltok != 0 && cnt > 0) ? (-(LB - M2 - __logf(S))) / (float)cnt * ((ce==ce)?1.f:1.f) : 0.f;
        }
      }
      gsync(bar, ++ph);
    }
  }

  // ================= tail: logits + CE for step 46 =================
  {
    const int t46 = SDD - 2;           // 46; h parity after step 46 = 46&1 = 0
    if (blk >= 32) {
      const int idx = (blk - 32) * 16 + (tid >> 6);
      if (idx < NTILES) {
        const int lane = tid & 63, ln = lane & 15, kq = lane >> 4;
        const unsigned short* wrow = w3b + ((size_t)idx * 16 + ln) * EDIM + kq * 8;
        const unsigned short* arow = hbf + ((size_t)0 * NL + 3) * NB * EDIM;
        const unsigned short* a0p = arow + (size_t)ln * EDIM + kq * 8;
        const unsigned short* a1p = a0p + 16 * EDIM;
        floatx4 acc0 = {0.f,0.f,0.f,0.f}, acc1 = {0.f,0.f,0.f,0.f};
#pragma unroll
        for (int c = 0; c < 16; ++c) {
          bf16x8 bf = ld_bf8(wrow + c * 32);
          bf16x8 a0 = ld_bf8(a0p + c * 32);
          bf16x8 a1 = ld_bf8(a1p + c * 32);
          acc0 = mfma16(a0, bf, acc0);
          acc1 = mfma16(a1, bf, acc1);
        }
        const float bv = p.b3[idx * 16 + ln];
        const int v = idx * 16 + ln;
#pragma unroll
        for (int mt = 0; mt < 2; ++mt) {
#pragma unroll
          for (int r = 0; r < 4; ++r) {
            const int b = mt * 16 + kq * 4 + r;
            const int ltok = p.dtok[b * SDD + t46 + 1];
            const int lab = (ltok > 0) ? ltok - 1 : 0;
            const float lv = (mt ? acc1[r] : acc0[r]) + bv;
            float m = lv, lb = (v == lab) ? lv : -1e30f;
#pragma unroll
            for (int st = 1; st < 16; st <<= 1) m = fmaxf(m, __shfl_xor(m, st, 64));
            float se = __expf(lv - m);
#pragma unroll
            for (int st = 1; st < 16; st <<= 1) se += __shfl_xor(se, st, 64);
#pragma unroll
            for (int st = 1; st < 16; st <<= 1) lb = fmaxf(lb, __shfl_xor(lb, st, 64));
            if (ln == 0) {
              float* cp = cep + ((size_t)b * NTILES + idx) * 4;
              cp[0] = m; cp[1] = se; cp[2] = lb;
            }
          }
        }
      }
    } else if (blk == 0 && (tid >> 6) == 8) {  // accumulate loss of step 45
      float v = ((tid & 63) < NB) ? wce[tid & 63] : 0.f;
      v = wred_sum(v);
      if ((tid & 63) == 0) total_loss += v;
    }
    gsync(bar, ++ph);
    if (blk >= 32 && blk < 64) {
      const int b = blk - 32;
      float m = -1e30f, s = 0.f, lb = -1e30f;
      if (tid < NTILES) {
        const float* cp = cep + ((size_t)b * NTILES + tid) * 4;
        m = cp[0]; s = cp[1]; lb = cp[2];
      }
      const int wid = tid >> 6, lane = tid & 63;
      const float M = wred_max(m);
      float sc = s * __expf(m - M);
      sc = wred_sum(sc);
      const float wl = wred_max(lb);
      if (lane == 0) { sm_parts[wid] = M; sm_parts[16 + wid] = sc; sm_parts[32 + wid] = wl; }
      __syncthreads();
      if (tid == 0) {
        float M2 = -1e30f, LB = -1e30f;
        for (int w = 0; w < 16; ++w) M2 = fmaxf(M2, sm_parts[w]);
        float S = 0.f;
        for (int w = 0; w < 16; ++w) S += sm_parts[16 + w] * __expf(sm_parts[w] - M2);
        for (int w = 0; w < 16; ++w) LB = fmaxf(LB, sm_parts[32 + w]);
        const int ltok = p.dtok[b * SDD + t46 + 1];
        int cnt = 0;
        for (int b2 = 0; b2 < NB; ++b2) cnt += (p.dtok[b2 * SDD + t46 + 1] != 0);
        wce[b] = (ltok != 0 && cnt > 0) ? (-(LB - M2 - __logf(S))) / (float)cnt : 0.f;
      }
    }
    gsync(bar, ++ph);
    if (blk == 0 && (tid >> 6) == 8) {
      float v = ((tid & 63) < NB) ? wce[tid & 63] : 0.f;
      v = wred_sum(v);
      if ((tid & 63) == 0) { total_loss += v; p.out[0] = total_loss; }
    }
  }
}

// ---- weight fp32->bf16 conversion + encoder embedding gather ----
__global__ __launch_bounds__(256) void convert_kernel(
    const float* Wih1, const float* Whh1, const float* Wih2, const float* Whh2,
    const float* W3, const float* emb1, const int* etok, char* wsb) {
  const long NW = (long)NL * 4 * EDIM * EDIM / 4;  // 1048576 float4 groups per array
  const long NW3 = (long)DVV * EDIM / 4;            // 2048000
  const long NEX = (long)NB * SEQ * EDIM / 4;       // 196608
  const long total = 4 * NW + NW3 + NEX;
  for (long g = (long)blockIdx.x * blockDim.x + threadIdx.x; g < total;
       g += (long)gridDim.x * blockDim.x) {
    float4 v;
    unsigned short* dst;
    long off;
    if (g < 4 * NW) {
      const float* src;
      if (g < NW)           { src = Wih1; dst = (unsigned short*)(wsb + WI1_OFF); off = g; }
      else if (g < 2 * NW)  { src = Whh1; dst = (unsigned short*)(wsb + WH1_OFF); off = g - NW; }
      else if (g < 3 * NW)  { src = Wih2; dst = (unsigned short*)(wsb + WI2_OFF); off = g - 2 * NW; }
      else                  { src = Whh2; dst = (unsigned short*)(wsb + WH2_OFF); off = g - 3 * NW; }
      v = *((const float4*)src + off);
    } else if (g < 4 * NW + NW3) {
      off = g - 4 * NW;
      v = *((const float4*)W3 + off);
      dst = (unsigned short*)(wsb + W3B_OFF);
    } else {
      const long e4 = g - 4 * NW - NW3;
      const int k4 = (int)(e4 & 127);
      const long bt = e4 >> 7;
      const int tok = etok[bt];
      v = *((const float4*)(emb1 + (size_t)tok * EDIM) + k4);
      dst = (unsigned short*)(wsb + EXB_OFF);
      off = bt * 128 + k4;
    }
    ushort4e o;
    o.x = f2bf(v.x); o.y = f2bf(v.y); o.z = f2bf(v.z); o.w = f2bf(v.w);
    *(ushort4e*)(dst + off * 4) = o;
  }
}

extern "C" void kernel_launch(void* const* d_in, const int* in_sizes, int n_in,
                              void* d_out, int out_size, void* d_ws, size_t ws_size,
                              hipStream_t stream) {
  (void)in_sizes; (void)n_in; (void)out_size; (void)ws_size;
  const int* etok = (const int*)d_in[0];
  const int* elen = (const int*)d_in[1];
  const int* dtok = (const int*)d_in[2];
  const float* emb1 = (const float*)d_in[3];
  const float* emb2 = (const float*)d_in[4];
  const float* Wih1 = (const float*)d_in[5];
  const float* Whh1 = (const float*)d_in[6];
  const float* bih1 = (const float*)d_in[7];
  const float* bhh1 = (const float*)d_in[8];
  const float* W1 = (const float*)d_in[9];
  const float* b1 = (const float*)d_in[10];
  const float* W2 = (const float*)d_in[11];
  const float* b2 = (const float*)d_in[12];
  const float* Wih2 = (const float*)d_in[13];
  const float* Whh2 = (const float*)d_in[14];
  const float* bih2 = (const float*)d_in[15];
  const float* bhh2 = (const float*)d_in[16];
  const float* W3 = (const float*)d_in[17];
  const float* b3 = (const float*)d_in[18];

  hipMemsetAsync(d_ws, 0, ZERO_BYTES, stream);
  hipLaunchKernelGGL(convert_kernel, dim3(4096), dim3(256), 0, stream,
                     Wih1, Whh1, Wih2, Whh2, W3, emb1, etok, (char*)d_ws);

  Params prm;
  prm.etok = etok; prm.elen = elen; prm.dtok = dtok;
  prm.emb2 = emb2;
  prm.bih1 = bih1; prm.bhh1 = bhh1;
  prm.W1 = W1; prm.b1 = b1; prm.W2 = W2; prm.b2 = b2;
  prm.bih2 = bih2; prm.bhh2 = bhh2;
  prm.b3 = b3;
  prm.out = (float*)d_out;
  prm.ws = (char*)d_ws;
  void* args[] = { &prm };
  hipLaunchCooperativeKernel((const void*)seq2seq_kernel, dim3(NBLK), dim3(NTHR), args, 0, stream);
}

// Round 3
// 6623.894 us; speedup vs baseline: 3.5364x; 3.3498x over previous
//
#include <hip/hip_runtime.h>

#define EDIM 512
#define NL 4
#define NB 32
#define SEQ 48
#define SDD 48
#define DVV 16000
#define NBLK 128
#define NTHR 1024
#define NTILES (DVV/16)   // 1000 vocab tiles of 16

// ---- ws layout (byte offsets) ----
#define BAR_OFF 0
#define WCE_OFF 256
#define H3F_OFF 512                                  // [32][512] f32 top-layer h (for attention)
#define HBF_OFF (H3F_OFF + NB*EDIM*4)                // [2][4][32][512] bf16 h (parity-buffered)
#define ZERO_BYTES (HBF_OFF + 2*NL*NB*EDIM*2)        // memset 0 .. here (bar + hbf zeros)
#define DEB_OFF ZERO_BYTES                           // [32][512] bf16 decoder LSTM input
#define CWS_OFF (DEB_OFF + NB*EDIM*2)                // [4][32][512] f32 c handoff enc->dec
#define UPO_OFF (CWS_OFF + (size_t)NL*NB*EDIM*4)     // [32][48][512] bf16 encoder outputs
#define EXB_OFF (UPO_OFF + (size_t)NB*SEQ*EDIM*2)    // [32][48][512] bf16 encoder embeddings
#define CEP_OFF (EXB_OFF + (size_t)NB*SEQ*EDIM*2)    // [32][1000][4] f32 logits partials
#define WI1_OFF (CEP_OFF + (size_t)NB*NTILES*4*4)
#define WH1_OFF (WI1_OFF + (size_t)NL*4*EDIM*EDIM*2)
#define WI2_OFF (WH1_OFF + (size_t)NL*4*EDIM*EDIM*2)
#define WH2_OFF (WI2_OFF + (size_t)NL*4*EDIM*EDIM*2)
#define W3B_OFF (WH2_OFF + (size_t)NL*4*EDIM*EDIM*2)
#define W2T_OFF (W3B_OFF + (size_t)DVV*EDIM*2)       // [560][512] bf16 W2 transposed
#define BS1_OFF (W2T_OFF + (size_t)560*EDIM*2)       // [4][2048] f32 bih1+bhh1
#define BS2_OFF (BS1_OFF + (size_t)NL*4*EDIM*4)      // [4][2048] f32 bih2+bhh2
// total ~54.9 MB of ws

typedef __bf16 bf16x8 __attribute__((ext_vector_type(8)));
typedef float floatx4 __attribute__((ext_vector_type(4)));
typedef unsigned int uint4e __attribute__((ext_vector_type(4)));
typedef unsigned short ushort4e __attribute__((ext_vector_type(4)));

struct Params {
  const int *etok, *elen, *dtok;
  const float *emb2;
  const float *W1, *b1, *b2;
  const float *b3;
  float* out;
  char* ws;
};

__device__ __forceinline__ float wred_sum(float v) {
#pragma unroll
  for (int i = 32; i > 0; i >>= 1) v += __shfl_xor(v, i, 64);
  return v;
}
__device__ __forceinline__ float wred_max(float v) {
#pragma unroll
  for (int i = 32; i > 0; i >>= 1) v = fmaxf(v, __shfl_xor(v, i, 64));
  return v;
}
__device__ __forceinline__ float sigm(float x) { return 1.f / (1.f + __expf(-x)); }
__device__ __forceinline__ float tanh_f(float x) { return 1.f - 2.f / (__expf(2.f * x) + 1.f); }
__device__ __forceinline__ unsigned short f2bf(float f) {  // RNE fp32->bf16
  unsigned int u = __float_as_uint(f);
  return (unsigned short)((u + 0x7fffu + ((u >> 16) & 1u)) >> 16);
}
__device__ __forceinline__ float bf2f(unsigned short u) {
  return __uint_as_float(((unsigned int)u) << 16);
}
__device__ __forceinline__ bf16x8 ld_bf8(const unsigned short* p) {
  return __builtin_bit_cast(bf16x8, *(const uint4e*)p);
}
__device__ __forceinline__ floatx4 mfma16(bf16x8 a, bf16x8 b, floatx4 c) {
  return __builtin_amdgcn_mfma_f32_16x16x32_bf16(a, b, c, 0, 0, 0);
}

// grid barrier: RELEASE arrival, RELAXED spin (no per-poll L2 invalidate!), one ACQUIRE at exit.
__device__ __forceinline__ void gsync(int* bar, int ph) {
  __syncthreads();
  if (threadIdx.x == 0) {
    __hip_atomic_fetch_add(&bar[0], 1, __ATOMIC_RELEASE, __HIP_MEMORY_SCOPE_AGENT);
    const int target = ph * NBLK;
    while (__hip_atomic_load(&bar[0], __ATOMIC_RELAXED, __HIP_MEMORY_SCOPE_AGENT) < target)
      __builtin_amdgcn_s_sleep(16);
    (void)__hip_atomic_load(&bar[0], __ATOMIC_ACQUIRE, __HIP_MEMORY_SCOPE_AGENT);
  }
  __syncthreads();
}

// One 4-gate LSTM GEMM slice: block computes gates[32 b][4 g][16 e] for e-range et*16..+16.
// waves: g = wid&3, ks = wid>>2 (K split 4: Wi lo/hi, Wh lo/hi). Partials -> sm_parts.
__device__ void gemm4g(const unsigned short* Wi, const unsigned short* Wh,
                       const unsigned short* xsrc, int xstr, const unsigned short* hsrc,
                       int et, int tid, float* parts) {
  const int wid = tid >> 6, lane = tid & 63, ln = lane & 15, kq = lane >> 4;
  const int g = wid & 3, ks = wid >> 2;
  const size_t n = (size_t)g * 512 + et * 16 + ln;
  const bool isH = (ks >= 2);
  const unsigned short* wr = (isH ? Wh : Wi) + n * EDIM;
  const unsigned short* ap = isH ? hsrc : xsrc;
  const int as = isH ? EDIM : xstr;
  const unsigned short* a0b = ap + (size_t)ln * as;
  const unsigned short* a1b = ap + (size_t)(16 + ln) * as;
  const int k0 = (ks & 1) * 256 + kq * 8;
  floatx4 acc0 = {0.f, 0.f, 0.f, 0.f}, acc1 = {0.f, 0.f, 0.f, 0.f};
#pragma unroll
  for (int c8 = 0; c8 < 8; ++c8) {
    const int kk = k0 + c8 * 32;
    bf16x8 bf = ld_bf8(wr + kk);
    bf16x8 a0 = ld_bf8(a0b + kk);
    bf16x8 a1 = ld_bf8(a1b + kk);
    acc0 = mfma16(a0, bf, acc0);
    acc1 = mfma16(a1, bf, acc1);
  }
  const int base = ((ks * 4 + g) * 2) * 256 + lane;
#pragma unroll
  for (int r = 0; r < 4; ++r) {
    parts[base + r * 64] = acc0[r];
    parts[base + 256 + r * 64] = acc1[r];
  }
}

// combine K-split partials + bias -> sm_gates[g*512 + b*16 + ln]
__device__ void gate_combine(const float* parts, float* gates,
                             const float* bsum, int et, int tid) {
  for (int v = tid; v < 2048; v += NTHR) {
    const int ln = v & 15, b = (v >> 4) & 31, g = v >> 9;
    const int mt = b >> 4, kq = (b >> 2) & 3, r = b & 3;
    const int lane = kq * 16 + ln;
    float s = 0.f;
#pragma unroll
    for (int ks = 0; ks < 4; ++ks)
      s += parts[((ks * 4 + g) * 2 + mt) * 256 + r * 64 + lane];
    gates[v] = s + bsum[g * 512 + et * 16 + ln];
  }
}

__global__ __launch_bounds__(NTHR) void seq2seq_kernel(Params p) {
  __shared__ float sm_parts[8192];   // 32 KB K-split partials / W2T matvec partials
  __shared__ float sm_gates[2048];   // 8 KB combined gates
  __shared__ float sm_c[2048];       // 8 KB c-state [l][b][ln] (enc: l=0 slot only)
  __shared__ float sm_attn[768];     // 0..47 raw att, 64.. upo_sum, 192..751 A=[ctx|emb]
  const int tid = threadIdx.x, blk = blockIdx.x;
  char* wsb = p.ws;
  int* bar = (int*)wsb;
  float* wce = (float*)(wsb + WCE_OFF);
  float* h3f = (float*)(wsb + H3F_OFF);
  unsigned short* hbf = (unsigned short*)(wsb + HBF_OFF);
  unsigned short* deb = (unsigned short*)(wsb + DEB_OFF);
  float* cws = (float*)(wsb + CWS_OFF);
  unsigned short* upo = (unsigned short*)(wsb + UPO_OFF);
  unsigned short* exb = (unsigned short*)(wsb + EXB_OFF);
  float* cep = (float*)(wsb + CEP_OFF);
  const unsigned short* wi1 = (const unsigned short*)(wsb + WI1_OFF);
  const unsigned short* wh1 = (const unsigned short*)(wsb + WH1_OFF);
  const unsigned short* wi2 = (const unsigned short*)(wsb + WI2_OFF);
  const unsigned short* wh2 = (const unsigned short*)(wsb + WH2_OFF);
  const unsigned short* w3b = (const unsigned short*)(wsb + W3B_OFF);
  const unsigned short* w2t = (const unsigned short*)(wsb + W2T_OFF);
  const float* bs1 = (const float*)(wsb + BS1_OFF);
  const float* bs2 = (const float*)(wsb + BS2_OFF);
  int ph = 0;
  float total_loss = 0.f;  // blk 0 only

  // ================= encoder: wavefront over d = t + li =================
  {
    const int li = blk >> 5, et = blk & 31;
    sm_c[tid] = 0.f; sm_c[tid + 1024] = 0.f;
    int mylen = 0;
    if (tid < 512) mylen = p.elen[tid >> 4];
    __syncthreads();
    for (int d = 0; d < SEQ + NL - 1; ++d) {
      const int t = d - li;
      if (t >= 0 && t < SEQ) {
        const int tp = t & 1, tq = tp ^ 1;
        const unsigned short* xsrc; int xstr;
        if (li == 0) { xsrc = exb + (size_t)t * EDIM; xstr = SEQ * EDIM; }
        else { xsrc = hbf + ((size_t)tp * NL + (li - 1)) * NB * EDIM; xstr = EDIM; }
        const unsigned short* hsrc = hbf + ((size_t)tq * NL + li) * NB * EDIM;
        gemm4g(wi1 + (size_t)li * 2048 * EDIM, wh1 + (size_t)li * 2048 * EDIM,
               xsrc, xstr, hsrc, et, tid, sm_parts);
        __syncthreads();
        gate_combine(sm_parts, sm_gates, bs1 + li * 2048, et, tid);
        __syncthreads();
        if (tid < 512) {
          const int b = tid >> 4, ln = tid & 15, e = et * 16 + ln;
          const bool act = t < mylen;
          const size_t hup = ((size_t)tp * NL + li) * NB * EDIM + (size_t)b * EDIM + e;
          const size_t hdn = ((size_t)tq * NL + li) * NB * EDIM + (size_t)b * EDIM + e;
          unsigned short hnew;
          if (act) {
            const float ig = sigm(sm_gates[tid]);
            const float fg = sigm(sm_gates[512 + tid]);
            const float gg = tanh_f(sm_gates[1024 + tid]);
            const float og = sigm(sm_gates[1536 + tid]);
            const float cn = fg * sm_c[tid] + ig * gg;
            sm_c[tid] = cn;
            const float h = og * tanh_f(cn);
            hnew = f2bf(h);
            if (li == 3) h3f[b * EDIM + e] = h;
          } else {
            hnew = hbf[hdn];
          }
          hbf[hup] = hnew;
          if (li == 3) upo[((size_t)b * SEQ + t) * EDIM + e] = act ? hnew : (unsigned short)0;
        }
        if (t == SEQ - 1) {  // dump c for decoder handoff (uniform branch)
          __syncthreads();
          if (tid < 512) {
            const int b = tid >> 4, ln = tid & 15;
            cws[((size_t)li * NB + b) * EDIM + et * 16 + ln] = sm_c[tid];
          }
        }
      }
      gsync(bar, ++ph);
    }
  }

  // ================= decoder: 47 steps =================
  for (int t = 0; t < SDD - 1; ++t) {
    const int pw = t & 1, pr = pw ^ 1;
    // ---- phase A: attention+de (blocks 0..31) || logits t-1 (blocks 32..94) ----
    if (blk < NB) {
      const int b = blk;
      const int wid = tid >> 6, lane = tid & 63;
      const float* h3r = h3f + b * EDIM + lane * 8;
      float hq[8];
      const float4 h4a = *(const float4*)h3r;
      const float4 h4b = *(const float4*)(h3r + 4);
      hq[0]=h4a.x; hq[1]=h4a.y; hq[2]=h4a.z; hq[3]=h4a.w;
      hq[4]=h4b.x; hq[5]=h4b.y; hq[6]=h4b.z; hq[7]=h4b.w;
      const int tok = p.dtok[b * SDD + t];
      if (tid < EDIM) sm_attn[240 + tid] = p.emb2[(size_t)tok * EDIM + tid];
      for (int s = wid; s < SEQ; s += 16) {
        const unsigned short* up = upo + ((size_t)b * SEQ + s) * EDIM + lane * 8;
        const uint4e uv = *(const uint4e*)up;
        float dv = 0.f, sv = 0.f;
#pragma unroll
        for (int j = 0; j < 4; ++j) {
          const unsigned int w = uv[j];
          const float lo = __uint_as_float(w << 16);
          const float hi = __uint_as_float(w & 0xffff0000u);
          dv = fmaf(lo, hq[2 * j], dv); sv += lo;
          dv = fmaf(hi, hq[2 * j + 1], dv); sv += hi;
        }
        dv = wred_sum(dv); sv = wred_sum(sv);
        if (lane == 0) { sm_attn[s] = dv; sm_attn[64 + s] = sv; }
      }
      if (t == 0 && tid >= 512) {  // load c handoff into LDS
#pragma unroll
        for (int j = 0; j < 4; ++j) {
          const int v = (tid - 512) * 4 + j;
          const int l = v >> 9, rem = v & 511, b2 = rem >> 4, ln = rem & 15;
          sm_c[v] = cws[((size_t)l * NB + b2) * EDIM + blk * 16 + ln];
        }
      }
      if (t >= 2 && blk == 0 && wid == 8) {  // accumulate loss of step t-2
        float v = (lane < NB) ? wce[lane] : 0.f;
        v = wred_sum(v);
        if (lane == 0) total_loss += v;
      }
      __syncthreads();
      if (wid == 0) {
        float y = -1e30f;
        if (lane < SEQ) {
          y = p.b1[lane];
          const float* w1r = p.W1 + lane * SEQ;
          for (int s = 0; s < SEQ; ++s) y = fmaf(sm_attn[s], w1r[s], y);
        }
        const float m = wred_max(y);
        const float ex = (lane < SEQ) ? __expf(y - m) : 0.f;
        const float S = wred_sum(ex);
        if (lane < SEQ) sm_attn[192 + lane] = (ex / S) * sm_attn[64 + lane];
      }
      __syncthreads();
      // de = A @ W2T (A = [ctx(48)|emb(512)] in sm_attn[192..751]); 4-way k-split
      {
        const int q = tid >> 8, tn = tid & 255, e2 = tn * 2;
        const int kb = q * 140;
        float a0 = (q == 0) ? p.b2[e2] : 0.f;
        float a1 = (q == 0) ? p.b2[e2 + 1] : 0.f;
        for (int k = kb; k < kb + 140; ++k) {
          const float av = sm_attn[192 + k];
          const unsigned int w = *(const unsigned int*)(w2t + (size_t)k * 512 + e2);
          a0 = fmaf(av, __uint_as_float(w << 16), a0);
          a1 = fmaf(av, __uint_as_float(w & 0xffff0000u), a1);
        }
        sm_parts[q * 512 + e2] = a0;
        sm_parts[q * 512 + e2 + 1] = a1;
      }
      __syncthreads();
      if (tid < 512) {
        const float s = sm_parts[tid] + sm_parts[512 + tid] + sm_parts[1024 + tid] + sm_parts[1536 + tid];
        deb[b * EDIM + tid] = f2bf(s);
      }
    } else if (t >= 1) {
      // logits for step t-1 via MFMA; h parity (t-1)&1 == pr
      const int idx = (blk - 32) * 16 + (tid >> 6);
      if (idx < NTILES) {
        const int lane = tid & 63, ln = lane & 15, kq = lane >> 4;
        const unsigned short* wrow = w3b + ((size_t)idx * 16 + ln) * EDIM + kq * 8;
        const unsigned short* arow = hbf + ((size_t)pr * NL + 3) * NB * EDIM;
        const unsigned short* a0p = arow + (size_t)ln * EDIM + kq * 8;
        const unsigned short* a1p = a0p + 16 * EDIM;
        floatx4 acc0 = {0.f,0.f,0.f,0.f}, acc1 = {0.f,0.f,0.f,0.f};
#pragma unroll
        for (int c = 0; c < 16; ++c) {
          bf16x8 bf = ld_bf8(wrow + c * 32);
          bf16x8 a0 = ld_bf8(a0p + c * 32);
          bf16x8 a1 = ld_bf8(a1p + c * 32);
          acc0 = mfma16(a0, bf, acc0);
          acc1 = mfma16(a1, bf, acc1);
        }
        const float bv = p.b3[idx * 16 + ln];
        const int v = idx * 16 + ln;
        const int step = t - 1;
#pragma unroll
        for (int mt = 0; mt < 2; ++mt) {
#pragma unroll
          for (int r = 0; r < 4; ++r) {
            const int b = mt * 16 + kq * 4 + r;
            const int ltok = p.dtok[b * SDD + step + 1];
            const int lab = (ltok > 0) ? ltok - 1 : 0;
            const float lv = (mt ? acc1[r] : acc0[r]) + bv;
            float m = lv, lb = (v == lab) ? lv : -1e30f;
#pragma unroll
            for (int st = 1; st < 16; st <<= 1) m = fmaxf(m, __shfl_xor(m, st, 64));
            float se = __expf(lv - m);
#pragma unroll
            for (int st = 1; st < 16; st <<= 1) se += __shfl_xor(se, st, 64);
#pragma unroll
            for (int st = 1; st < 16; st <<= 1) lb = fmaxf(lb, __shfl_xor(lb, st, 64));
            if (ln == 0) {
              float* cp = cep + ((size_t)b * NTILES + idx) * 4;
              cp[0] = m; cp[1] = se; cp[2] = lb;
            }
          }
        }
      }
    }
    gsync(bar, ++ph);
    // ---- phases G0..G3 ----
    for (int l = 0; l < NL; ++l) {
      if (blk < NB) {
        const unsigned short* xsrc = (l == 0) ? deb : hbf + ((size_t)pw * NL + (l - 1)) * NB * EDIM;
        const unsigned short* hsrc = hbf + ((size_t)pr * NL + l) * NB * EDIM;
        gemm4g(wi2 + (size_t)l * 2048 * EDIM, wh2 + (size_t)l * 2048 * EDIM,
               xsrc, EDIM, hsrc, blk, tid, sm_parts);
        __syncthreads();
        gate_combine(sm_parts, sm_gates, bs2 + l * 2048, blk, tid);
        __syncthreads();
        if (tid < 512) {
          const int b = tid >> 4, ln = tid & 15, e = blk * 16 + ln;
          const float ig = sigm(sm_gates[tid]);
          const float fg = sigm(sm_gates[512 + tid]);
          const float gg = tanh_f(sm_gates[1024 + tid]);
          const float og = sigm(sm_gates[1536 + tid]);
          const float cn = fg * sm_c[l * 512 + tid] + ig * gg;
          sm_c[l * 512 + tid] = cn;
          const float h = og * tanh_f(cn);
          hbf[((size_t)pw * NL + l) * NB * EDIM + (size_t)b * EDIM + e] = f2bf(h);
          if (l == 3) h3f[b * EDIM + e] = h;
        }
      } else if (l == 0 && blk >= 32 && blk < 64 && t >= 1) {
        // combine logits partials of step t-1 -> wce[b]
        const int b = blk - 32;
        float m = -1e30f, s = 0.f, lb = -1e30f;
        if (tid < NTILES) {
          const float* cp = cep + ((size_t)b * NTILES + tid) * 4;
          m = cp[0]; s = cp[1]; lb = cp[2];
        }
        const int wid = tid >> 6, lane = tid & 63;
        const float M = wred_max(m);
        float sc = s * __expf(m - M);
        sc = wred_sum(sc);
        const float wl = wred_max(lb);
        if (lane == 0) { sm_parts[wid] = M; sm_parts[16 + wid] = sc; sm_parts[32 + wid] = wl; }
        __syncthreads();
        if (tid == 0) {
          float M2 = -1e30f, LB = -1e30f;
          for (int w = 0; w < 16; ++w) M2 = fmaxf(M2, sm_parts[w]);
          float S = 0.f;
          for (int w = 0; w < 16; ++w) S += sm_parts[16 + w] * __expf(sm_parts[w] - M2);
          for (int w = 0; w < 16; ++w) LB = fmaxf(LB, sm_parts[32 + w]);
          const int step = t - 1;
          const int ltok = p.dtok[b * SDD + step + 1];
          int cnt = 0;
          for (int b2 = 0; b2 < NB; ++b2) cnt += (p.dtok[b2 * SDD + step + 1] != 0);
          wce[b] = (ltok != 0 && cnt > 0) ? (-(LB - M2 - __logf(S))) / (float)cnt : 0.f;
        }
      }
      gsync(bar, ++ph);
    }
  }

  // ================= tail: logits + CE for step 46 =================
  {
    const int t46 = SDD - 2;           // h parity after step 46 = 0
    if (blk >= 32) {
      const int idx = (blk - 32) * 16 + (tid >> 6);
      if (idx < NTILES) {
        const int lane = tid & 63, ln = lane & 15, kq = lane >> 4;
        const unsigned short* wrow = w3b + ((size_t)idx * 16 + ln) * EDIM + kq * 8;
        const unsigned short* arow = hbf + ((size_t)0 * NL + 3) * NB * EDIM;
        const unsigned short* a0p = arow + (size_t)ln * EDIM + kq * 8;
        const unsigned short* a1p = a0p + 16 * EDIM;
        floatx4 acc0 = {0.f,0.f,0.f,0.f}, acc1 = {0.f,0.f,0.f,0.f};
#pragma unroll
        for (int c = 0; c < 16; ++c) {
          bf16x8 bf = ld_bf8(wrow + c * 32);
          bf16x8 a0 = ld_bf8(a0p + c * 32);
          bf16x8 a1 = ld_bf8(a1p + c * 32);
          acc0 = mfma16(a0, bf, acc0);
          acc1 = mfma16(a1, bf, acc1);
        }
        const float bv = p.b3[idx * 16 + ln];
        const int v = idx * 16 + ln;
#pragma unroll
        for (int mt = 0; mt < 2; ++mt) {
#pragma unroll
          for (int r = 0; r < 4; ++r) {
            const int b = mt * 16 + kq * 4 + r;
            const int ltok = p.dtok[b * SDD + t46 + 1];
            const int lab = (ltok > 0) ? ltok - 1 : 0;
            const float lv = (mt ? acc1[r] : acc0[r]) + bv;
            float m = lv, lb = (v == lab) ? lv : -1e30f;
#pragma unroll
            for (int st = 1; st < 16; st <<= 1) m = fmaxf(m, __shfl_xor(m, st, 64));
            float se = __expf(lv - m);
#pragma unroll
            for (int st = 1; st < 16; st <<= 1) se += __shfl_xor(se, st, 64);
#pragma unroll
            for (int st = 1; st < 16; st <<= 1) lb = fmaxf(lb, __shfl_xor(lb, st, 64));
            if (ln == 0) {
              float* cp = cep + ((size_t)b * NTILES + idx) * 4;
              cp[0] = m; cp[1] = se; cp[2] = lb;
            }
          }
        }
      }
    } else if (blk == 0 && (tid >> 6) == 8) {  // accumulate loss of step 45
      float v = ((tid & 63) < NB) ? wce[tid & 63] : 0.f;
      v = wred_sum(v);
      if ((tid & 63) == 0) total_loss += v;
    }
    gsync(bar, ++ph);
    if (blk >= 32 && blk < 64) {
      const int b = blk - 32;
      float m = -1e30f, s = 0.f, lb = -1e30f;
      if (tid < NTILES) {
        const float* cp = cep + ((size_t)b * NTILES + tid) * 4;
        m = cp[0]; s = cp[1]; lb = cp[2];
      }
      const int wid = tid >> 6, lane = tid & 63;
      const float M = wred_max(m);
      float sc = s * __expf(m - M);
      sc = wred_sum(sc);
      const float wl = wred_max(lb);
      if (lane == 0) { sm_parts[wid] = M; sm_parts[16 + wid] = sc; sm_parts[32 + wid] = wl; }
      __syncthreads();
      if (tid == 0) {
        float M2 = -1e30f, LB = -1e30f;
        for (int w = 0; w < 16; ++w) M2 = fmaxf(M2, sm_parts[w]);
        float S = 0.f;
        for (int w = 0; w < 16; ++w) S += sm_parts[16 + w] * __expf(sm_parts[w] - M2);
        for (int w = 0; w < 16; ++w) LB = fmaxf(LB, sm_parts[32 + w]);
        const int ltok = p.dtok[b * SDD + t46 + 1];
        int cnt = 0;
        for (int b2 = 0; b2 < NB; ++b2) cnt += (p.dtok[b2 * SDD + t46 + 1] != 0);
        wce[b] = (ltok != 0 && cnt > 0) ? (-(LB - M2 - __logf(S))) / (float)cnt : 0.f;
      }
    }
    gsync(bar, ++ph);
    if (blk == 0 && (tid >> 6) == 8) {
      float v = ((tid & 63) < NB) ? wce[tid & 63] : 0.f;
      v = wred_sum(v);
      if ((tid & 63) == 0) { total_loss += v; p.out[0] = total_loss; }
    }
  }
}

// ---- weight fp32->bf16 conversion, W2 transpose, bias pre-sum, encoder embedding gather ----
__global__ __launch_bounds__(256) void convert_kernel(
    const float* Wih1, const float* Whh1, const float* Wih2, const float* Whh2,
    const float* W3, const float* emb1, const int* etok, const float* W2,
    const float* bih1, const float* bhh1, const float* bih2, const float* bhh2,
    char* wsb) {
  const long NW = (long)NL * 4 * EDIM * EDIM / 4;   // 1048576 groups per LSTM weight array
  const long NW3 = (long)DVV * EDIM / 4;            // 2048000
  const long NEX = (long)NB * SEQ * EDIM / 4;       // 196608
  const long NW2T = (long)560 * EDIM / 4;           // 71680
  const long BF16_TOTAL = 4 * NW + NW3 + NEX + NW2T;
  const long NBS = (long)NL * 4 * EDIM / 4;         // 2048 per bias array
  const long total = BF16_TOTAL + 2 * NBS;
  for (long g = (long)blockIdx.x * blockDim.x + threadIdx.x; g < total;
       g += (long)gridDim.x * blockDim.x) {
    if (g >= BF16_TOTAL) {  // bias pre-sum (fp32)
      long off = g - BF16_TOTAL;
      const float *A, *Bp; float* D;
      if (off < NBS) { A = bih1; Bp = bhh1; D = (float*)(wsb + BS1_OFF); }
      else { off -= NBS; A = bih2; Bp = bhh2; D = (float*)(wsb + BS2_OFF); }
      float4 x = ((const float4*)A)[off];
      const float4 y = ((const float4*)Bp)[off];
      x.x += y.x; x.y += y.y; x.z += y.z; x.w += y.w;
      ((float4*)D)[off] = x;
      continue;
    }
    float4 v;
    unsigned short* dst;
    long off;
    if (g < 4 * NW) {
      const float* src;
      if (g < NW)           { src = Wih1; dst = (unsigned short*)(wsb + WI1_OFF); off = g; }
      else if (g < 2 * NW)  { src = Whh1; dst = (unsigned short*)(wsb + WH1_OFF); off = g - NW; }
      else if (g < 3 * NW)  { src = Wih2; dst = (unsigned short*)(wsb + WI2_OFF); off = g - 2 * NW; }
      else                  { src = Whh2; dst = (unsigned short*)(wsb + WH2_OFF); off = g - 3 * NW; }
      v = *((const float4*)src + off);
    } else if (g < 4 * NW + NW3) {
      off = g - 4 * NW;
      v = *((const float4*)W3 + off);
      dst = (unsigned short*)(wsb + W3B_OFF);
    } else if (g < 4 * NW + NW3 + NEX) {
      const long e4 = g - 4 * NW - NW3;
      const int k4 = (int)(e4 & 127);
      const long bt = e4 >> 7;
      const int tok = etok[bt];
      v = *((const float4*)(emb1 + (size_t)tok * EDIM) + k4);
      dst = (unsigned short*)(wsb + EXB_OFF);
      off = bt * 128 + k4;
    } else {
      off = g - 4 * NW - NW3 - NEX;           // W2 transpose: dst[k][e], 4 e per group
      const int e = (int)(off & 127) * 4;
      const int k = (int)(off >> 7);
      v.x = W2[(size_t)(e + 0) * (SEQ + EDIM) + k];
      v.y = W2[(size_t)(e + 1) * (SEQ + EDIM) + k];
      v.z = W2[(size_t)(e + 2) * (SEQ + EDIM) + k];
      v.w = W2[(size_t)(e + 3) * (SEQ + EDIM) + k];
      dst = (unsigned short*)(wsb + W2T_OFF);
    }
    ushort4e o;
    o.x = f2bf(v.x); o.y = f2bf(v.y); o.z = f2bf(v.z); o.w = f2bf(v.w);
    *(ushort4e*)(dst + off * 4) = o;
  }
}

extern "C" void kernel_launch(void* const* d_in, const int* in_sizes, int n_in,
                              void* d_out, int out_size, void* d_ws, size_t ws_size,
                              hipStream_t stream) {
  (void)in_sizes; (void)n_in; (void)out_size; (void)ws_size;
  const int* etok = (const int*)d_in[0];
  const int* elen = (const int*)d_in[1];
  const int* dtok = (const int*)d_in[2];
  const float* emb1 = (const float*)d_in[3];
  const float* emb2 = (const float*)d_in[4];
  const float* Wih1 = (const float*)d_in[5];
  const float* Whh1 = (const float*)d_in[6];
  const float* bih1 = (const float*)d_in[7];
  const float* bhh1 = (const float*)d_in[8];
  const float* W1 = (const float*)d_in[9];
  const float* b1 = (const float*)d_in[10];
  const float* W2 = (const float*)d_in[11];
  const float* b2 = (const float*)d_in[12];
  const float* Wih2 = (const float*)d_in[13];
  const float* Whh2 = (const float*)d_in[14];
  const float* bih2 = (const float*)d_in[15];
  const float* bhh2 = (const float*)d_in[16];
  const float* W3 = (const float*)d_in[17];
  const float* b3 = (const float*)d_in[18];

  hipMemsetAsync(d_ws, 0, ZERO_BYTES, stream);
  hipLaunchKernelGGL(convert_kernel, dim3(4096), dim3(256), 0, stream,
                     Wih1, Whh1, Wih2, Whh2, W3, emb1, etok, W2,
                     bih1, bhh1, bih2, bhh2, (char*)d_ws);

  Params prm;
  prm.etok = etok; prm.elen = elen; prm.dtok = dtok;
  prm.emb2 = emb2;
  prm.W1 = W1; prm.b1 = b1; prm.b2 = b2;
  prm.b3 = b3;
  prm.out = (float*)d_out;
  prm.ws = (char*)d_ws;
  void* args[] = { &prm };
  hipLaunchCooperativeKernel((const void*)seq2seq_kernel, dim3(NBLK), dim3(NTHR), args, 0, stream);
}